// Round 1
// baseline (1632.168 us; speedup 1.0000x reference)
//
#include <hip/hip_runtime.h>
#include <cstddef>

// ---------------- problem constants ----------------
constexpr int CC    = 192;   // channels
constexpr int NHEAD = 6;
constexpr int HD    = 32;    // head dim
constexpr int NTOK  = 49;    // tokens per 7x7 window
constexpr int IMG   = 112;
constexpr int TOTWIN = 4096;           // 16 batches * 256 windows
constexpr int M_TOK  = TOTWIN * NTOK;  // 200704 rows
constexpr size_t QKV_PLANE = (size_t)TOTWIN * NHEAD * NTOK * HD; // 38,535,168 floats
constexpr float QSCALE = 0.17677669529663687f; // 32^-0.5

// token id -> (batch, window coords, intra-window coords)
__device__ __forceinline__ void map_token(int m, int& b, int& wh, int& ww, int& ih, int& iw) {
    int win = m / NTOK;
    int tok = m - win * NTOK;
    b  = win >> 8;             // 256 windows per batch
    int wib = win & 255;
    wh = wib >> 4; ww = wib & 15;
    ih = tok / 7;  iw = tok - ih * 7;
}

// ---------------- kernel 1: QKV projection (gather + GEMM + bias + q-scale) ----------------
// C[m, n] = sum_k A[m,k] * Wqkv[n,k] + bias[n];  A gathered through roll(-3,-3)+window partition
// out layout: qkv_ws[which][win][head][tok][d]
__global__ __launch_bounds__(256, 4)
void qkv_gemm(const float* __restrict__ x, const float* __restrict__ w,
              const float* __restrict__ bias, float* __restrict__ qkv_ws) {
    __shared__ float As[64][64];   // [k][row]  (k-major: conflict-free float4 reads)
    __shared__ float Bs[64][64];   // [k][col]
    const int nt = blockIdx.x;     // 0..8   (N = 576)
    const int mt = blockIdx.y;     // 0..3135
    const int t  = threadIdx.x;
    const int tx = t & 15, ty = t >> 4;   // 16x16 threads, 4x4 micro-tile
    const int lr = t & 63, kq = t >> 6;   // load-phase: row, k-quarter

    int b, wh, ww, ih, iw;
    map_token(mt * 64 + lr, b, wh, ww, ih, iw);
    int sh = wh * 7 + ih + 3; if (sh >= IMG) sh -= IMG;   // roll(-3): src = (pos+3) % 112
    int sw = ww * 7 + iw + 3; if (sw >= IMG) sw -= IMG;
    const float* arow = x + ((size_t)((b * IMG + sh) * IMG + sw)) * CC;
    const float* brow = w + (size_t)(nt * 64 + lr) * CC;

    float acc[4][4] = {};
    for (int kc = 0; kc < CC; kc += 64) {
        #pragma unroll
        for (int q4 = 0; q4 < 4; ++q4) {
            int kk = kq * 16 + q4 * 4;
            float4 av = *reinterpret_cast<const float4*>(arow + kc + kk);
            As[kk+0][lr] = av.x; As[kk+1][lr] = av.y; As[kk+2][lr] = av.z; As[kk+3][lr] = av.w;
            float4 bv = *reinterpret_cast<const float4*>(brow + kc + kk);
            Bs[kk+0][lr] = bv.x; Bs[kk+1][lr] = bv.y; Bs[kk+2][lr] = bv.z; Bs[kk+3][lr] = bv.w;
        }
        __syncthreads();
        #pragma unroll 8
        for (int k = 0; k < 64; ++k) {
            float4 a4 = *reinterpret_cast<const float4*>(&As[k][ty * 4]);
            float4 b4 = *reinterpret_cast<const float4*>(&Bs[k][tx * 4]);
            float av[4] = {a4.x, a4.y, a4.z, a4.w};
            float bv[4] = {b4.x, b4.y, b4.z, b4.w};
            #pragma unroll
            for (int i = 0; i < 4; ++i)
                #pragma unroll
                for (int j = 0; j < 4; ++j)
                    acc[i][j] = fmaf(av[i], bv[j], acc[i][j]);
        }
        __syncthreads();
    }

    // epilogue: bias, q-scale, scatter to [which][win][head][tok][d]
    const int n0   = nt * 64 + tx * 4;
    const int which = n0 / CC;
    const int rem  = n0 - which * CC;
    const int head = rem >> 5, d = rem & 31;
    float4 bv4 = *reinterpret_cast<const float4*>(bias + n0);
    const float bb[4] = {bv4.x, bv4.y, bv4.z, bv4.w};
    const float scale = (which == 0) ? QSCALE : 1.0f;
    float* basep = qkv_ws + (size_t)which * QKV_PLANE;
    #pragma unroll
    for (int i = 0; i < 4; ++i) {
        int m = mt * 64 + ty * 4 + i;
        int win = m / NTOK, tok = m - win * NTOK;
        float4 val;
        val.x = (acc[i][0] + bb[0]) * scale;
        val.y = (acc[i][1] + bb[1]) * scale;
        val.z = (acc[i][2] + bb[2]) * scale;
        val.w = (acc[i][3] + bb[3]) * scale;
        *reinterpret_cast<float4*>(basep + (((size_t)(win * NHEAD + head)) * NTOK + tok) * HD + d) = val;
    }
}

// ---------------- kernel 2: windowed attention, one block per (window, head) ----------------
__global__ __launch_bounds__(256, 4)
void attn_win(const float* __restrict__ qkv_ws, const float* __restrict__ rbt,
              float* __restrict__ attn_ws) {
    __shared__ float qs[NTOK * HD];
    __shared__ float ks[NTOK * HD];
    __shared__ float vs[NTOK * HD];
    __shared__ float Ss[NTOK * NTOK];
    const int win = blockIdx.x, h = blockIdx.y;
    const int t = threadIdx.x;
    const float* qp = qkv_ws + (size_t)(win * NHEAD + h) * (NTOK * HD);
    const float* kp = qp + QKV_PLANE;
    const float* vp = qp + 2 * QKV_PLANE;
    for (int i = t; i < (NTOK * HD) / 4; i += 256) {
        reinterpret_cast<float4*>(qs)[i] = reinterpret_cast<const float4*>(qp)[i];
        reinterpret_cast<float4*>(ks)[i] = reinterpret_cast<const float4*>(kp)[i];
        reinterpret_cast<float4*>(vs)[i] = reinterpret_cast<const float4*>(vp)[i];
    }
    __syncthreads();

    const int wib = win & 255, wh = wib >> 4, ww = wib & 15;
    // S = q k^T + rel_pos_bias + shift_mask   (bias index & mask computed analytically)
    for (int e = t; e < NTOK * NTOK; e += 256) {
        int qr = e / 49, kc = e - qr * 49;
        float s = 0.f;
        #pragma unroll
        for (int d4 = 0; d4 < HD; d4 += 4) {
            float4 qa = *reinterpret_cast<const float4*>(qs + qr * HD + d4);
            float4 ka = *reinterpret_cast<const float4*>(ks + kc * HD + d4);
            s += qa.x * ka.x + qa.y * ka.y + qa.z * ka.z + qa.w * ka.w;
        }
        int qh = qr / 7, qw = qr - qh * 7, kh = kc / 7, kw = kc - kh * 7;
        s += rbt[((qh - kh + 6) * 13 + (qw - kw + 6)) * NHEAD + h];
        // shift-mask regions: h/w bands split at 105 (=112-7) and 109 (=112-3)
        int ghq = wh * 7 + qh, gwq = ww * 7 + qw, ghk = wh * 7 + kh, gwk = ww * 7 + kw;
        int rq = (ghq < 105 ? 0 : (ghq < 109 ? 3 : 6)) + (gwq < 105 ? 0 : (gwq < 109 ? 1 : 2));
        int rk = (ghk < 105 ? 0 : (ghk < 109 ? 3 : 6)) + (gwk < 105 ? 0 : (gwk < 109 ? 1 : 2));
        if (rq != rk) s -= 100.f;
        Ss[e] = s;
    }
    __syncthreads();

    // softmax per row (49 rows, one thread each — small phase)
    if (t < NTOK) {
        float mx = -1e30f;
        for (int kc = 0; kc < NTOK; ++kc) mx = fmaxf(mx, Ss[t * 49 + kc]);
        float sum = 0.f;
        for (int kc = 0; kc < NTOK; ++kc) { float ev = __expf(Ss[t * 49 + kc] - mx); Ss[t * 49 + kc] = ev; sum += ev; }
        float inv = 1.f / sum;
        for (int kc = 0; kc < NTOK; ++kc) Ss[t * 49 + kc] *= inv;
    }
    __syncthreads();

    // O = S @ v  -> attn_ws[win][tok][h*32+d]  (proj-ready layout)
    for (int e4 = t; e4 < NTOK * 8; e4 += 256) {
        int orow = e4 >> 3, d4 = (e4 & 7) * 4;
        float ax = 0.f, ay = 0.f, az = 0.f, aw = 0.f;
        for (int kc = 0; kc < NTOK; ++kc) {
            float s = Ss[orow * 49 + kc];
            float4 v4 = *reinterpret_cast<const float4*>(vs + kc * HD + d4);
            ax = fmaf(s, v4.x, ax); ay = fmaf(s, v4.y, ay);
            az = fmaf(s, v4.z, az); aw = fmaf(s, v4.w, aw);
        }
        float4 o = {ax, ay, az, aw};
        *reinterpret_cast<float4*>(attn_ws + ((size_t)(win * NTOK + orow)) * CC + h * HD + d4) = o;
    }
}

// ---------------- kernel 3: output projection + window reverse + roll(+3,+3) ----------------
__global__ __launch_bounds__(256, 4)
void proj_gemm(const float* __restrict__ a, const float* __restrict__ w,
               const float* __restrict__ bias, float* __restrict__ out) {
    __shared__ float As[64][64];
    __shared__ float Bs[64][64];
    const int nt = blockIdx.x;     // 0..2  (N = 192)
    const int mt = blockIdx.y;     // 0..3135
    const int t  = threadIdx.x;
    const int tx = t & 15, ty = t >> 4;
    const int lr = t & 63, kq = t >> 6;

    const float* arow = a + (size_t)(mt * 64 + lr) * CC;
    const float* brow = w + (size_t)(nt * 64 + lr) * CC;

    float acc[4][4] = {};
    for (int kc = 0; kc < CC; kc += 64) {
        #pragma unroll
        for (int q4 = 0; q4 < 4; ++q4) {
            int kk = kq * 16 + q4 * 4;
            float4 av = *reinterpret_cast<const float4*>(arow + kc + kk);
            As[kk+0][lr] = av.x; As[kk+1][lr] = av.y; As[kk+2][lr] = av.z; As[kk+3][lr] = av.w;
            float4 bv = *reinterpret_cast<const float4*>(brow + kc + kk);
            Bs[kk+0][lr] = bv.x; Bs[kk+1][lr] = bv.y; Bs[kk+2][lr] = bv.z; Bs[kk+3][lr] = bv.w;
        }
        __syncthreads();
        #pragma unroll 8
        for (int k = 0; k < 64; ++k) {
            float4 a4 = *reinterpret_cast<const float4*>(&As[k][ty * 4]);
            float4 b4 = *reinterpret_cast<const float4*>(&Bs[k][tx * 4]);
            float av[4] = {a4.x, a4.y, a4.z, a4.w};
            float bv[4] = {b4.x, b4.y, b4.z, b4.w};
            #pragma unroll
            for (int i = 0; i < 4; ++i)
                #pragma unroll
                for (int j = 0; j < 4; ++j)
                    acc[i][j] = fmaf(av[i], bv[j], acc[i][j]);
        }
        __syncthreads();
    }

    const int n0 = nt * 64 + tx * 4;
    float4 bv4 = *reinterpret_cast<const float4*>(bias + n0);
    #pragma unroll
    for (int i = 0; i < 4; ++i) {
        int m = mt * 64 + ty * 4 + i;
        int b, wh, ww, ih, iw;
        map_token(m, b, wh, ww, ih, iw);
        int fh = wh * 7 + ih + 3; if (fh >= IMG) fh -= IMG;  // window reverse + roll(+3)
        int fw = ww * 7 + iw + 3; if (fw >= IMG) fw -= IMG;
        float4 val;
        val.x = acc[i][0] + bv4.x;
        val.y = acc[i][1] + bv4.y;
        val.z = acc[i][2] + bv4.z;
        val.w = acc[i][3] + bv4.w;
        *reinterpret_cast<float4*>(out + ((size_t)((b * IMG + fh) * IMG + fw)) * CC + n0) = val;
    }
}

// ---------------- launcher ----------------
extern "C" void kernel_launch(void* const* d_in, const int* in_sizes, int n_in,
                              void* d_out, int out_size, void* d_ws, size_t ws_size,
                              hipStream_t stream) {
    const float* x     = (const float*)d_in[0];
    const float* qkvw  = (const float*)d_in[1];
    const float* qkvb  = (const float*)d_in[2];
    const float* projw = (const float*)d_in[3];
    const float* projb = (const float*)d_in[4];
    const float* relb  = (const float*)d_in[5];
    float* out = (float*)d_out;

    float* qkv_ws  = (float*)d_ws;                       // 3 * 38,535,168 floats
    float* attn_ws = qkv_ws + 3 * QKV_PLANE;             // 38,535,168 floats
    // total workspace: 616,562,688 bytes

    qkv_gemm<<<dim3(9, 3136), 256, 0, stream>>>(x, qkvw, qkvb, qkv_ws);
    attn_win<<<dim3(TOTWIN, NHEAD), 256, 0, stream>>>(qkv_ws, relb, attn_ws);
    proj_gemm<<<dim3(3, 3136), 256, 0, stream>>>(attn_ws, projw, projb, out);
}

// Round 6
// 598.529 us; speedup vs baseline: 2.7270x; 2.7270x over previous
//
#include <hip/hip_runtime.h>
#include <cstddef>
#include <cstdint>

typedef __attribute__((ext_vector_type(4))) float f32x4;
typedef __attribute__((ext_vector_type(8))) short s16x8;

constexpr int CC = 192, NHEAD = 6, HD = 32, NTOK = 49, IMG = 112, TOTWIN = 4096;
constexpr int MTOK = TOTWIN * NTOK;            // 200704
constexpr float QSCALE = 0.17677669529663687f; // 32^-0.5
// fragment-major planes: q/k: [task][qt(4)][lane(64)][8]; v: [task][s(2)][ni(2)][lane][8]
constexpr size_t PLANE_U16 = (size_t)TOTWIN * NHEAD * 4 * 64 * 8; // 50,331,648 u16 each
constexpr int WQ_SLOTS = 6 * 36 * 64;  // 13824
constexpr int WP_SLOTS = 6 * 12 * 64;  // 4608
constexpr int TBL_N    = 6 * 4 * 64 * 64; // 98304

__device__ __forceinline__ unsigned short bfh(float f) {
    unsigned u = __float_as_uint(f);
    return (unsigned short)((u + 0x7FFFu + ((u >> 16) & 1u)) >> 16);
}
__device__ __forceinline__ float bff(unsigned short h) {
    return __uint_as_float(((unsigned)h) << 16);
}
#define MFMA_BF16(acc, a, b) \
    (acc) = __builtin_amdgcn_mfma_f32_16x16x32_bf16((a), (b), (acc), 0, 0, 0)

// gathered x-row offset: roll(-3,-3) + 7x7 window partition
__device__ __forceinline__ int arow_off_qkv(int m) {
    int win = m / NTOK, tok = m - win * NTOK;
    int b = win >> 8, wib = win & 255;
    int ih = tok / 7, iw = tok - ih * 7;
    int sh = (wib >> 4) * 7 + ih + 3; if (sh >= IMG) sh -= IMG;
    int sw = (wib & 15) * 7 + iw + 3; if (sw >= IMG) sw -= IMG;
    return ((b * IMG + sh) * IMG + sw) * CC;
}

// ---------------- prep: weight frag-planes (hi/lo) + bias/mask table ----------------
__global__ void prep(const float* __restrict__ wq, const float* __restrict__ wp,
                     const float* __restrict__ rbt,
                     short* __restrict__ wqh, short* __restrict__ wql,
                     short* __restrict__ wph, short* __restrict__ wpl,
                     float* __restrict__ tbl) {
    int i = blockIdx.x * 256 + threadIdx.x;
    if (i < WQ_SLOTS + WP_SLOTS) {
        const float* src; short *dh, *dl; int slot, nfr;
        if (i < WQ_SLOTS) { src = wq; dh = wqh; dl = wql; slot = i; nfr = 36; }
        else              { src = wp; dh = wph; dl = wpl; slot = i - WQ_SLOTS; nfr = 12; }
        int kt = slot / (nfr * 64), rem = slot % (nfr * 64), f = rem >> 6, lane = rem & 63;
        int n = f * 16 + (lane & 15), k = kt * 32 + (lane >> 4) * 8;
        s16x8 hv, lv;
        #pragma unroll
        for (int j = 0; j < 8; ++j) {
            float v = src[n * CC + k + j];
            unsigned short h = bfh(v);
            hv[j] = (short)h; lv[j] = (short)bfh(v - bff(h));
        }
        *reinterpret_cast<s16x8*>(dh + (size_t)slot * 8) = hv;
        *reinterpret_cast<s16x8*>(dl + (size_t)slot * 8) = lv;
    }
    int ti = i - (WQ_SLOTS + WP_SLOTS);
    if (ti >= 0 && ti < TBL_N) {
        int h = ti / (4 * 4096), rem = ti % (4 * 4096), cls = rem >> 12, e = rem & 4095;
        int kr = e >> 6, q = e & 63;
        float v;
        if (kr >= NTOK) v = -1e30f;          // padded k: excluded from softmax
        else if (q >= NTOK) v = 0.f;         // padded q: rows discarded
        else {
            int qh = q / 7, qw = q % 7, kh = kr / 7, kw = kr % 7;
            float b = rbt[((qh - kh + 6) * 13 + (qw - kw + 6)) * NHEAD + h];
            int rq = ((cls >> 1) ? (qh < 4 ? 3 : 6) : 0) + ((cls & 1) ? (qw < 4 ? 1 : 2) : 0);
            int rk = ((cls >> 1) ? (kh < 4 ? 3 : 6) : 0) + ((cls & 1) ? (kw < 4 ? 1 : 2) : 0);
            v = (rq != rk) ? b - 100.f : b;
        }
        tbl[ti] = v;
    }
}

// ---------------- bf16x3 GEMM computing C^T (A-operand = weights) ----------------
// MODE 0: A-src = x (gathered rows), N=576 in 3 nblk; epilogue -> q/k/v frag planes (bf16)
// MODE 1: A-src = attn-O fp32 [m][192]; epilogue -> d_out via window-reverse+roll (+bias)
template<int MODE>
__global__ __launch_bounds__(256, 2)
void gemm_swapped(const float* __restrict__ Asrc,
                  const short* __restrict__ Wh, const short* __restrict__ Wl,
                  const float* __restrict__ bias,
                  short* __restrict__ qpl, short* __restrict__ kpl, short* __restrict__ vpl,
                  float* __restrict__ outp) {
    __shared__ s16x8 AhS[512], AlS[512], BhS[768], BlS[768]; // 40 KiB
    int mt, nblk;
    if (MODE == 0) {  // XCD swizzle: co-locate the 3 nblk sharing one A-tile (4704 % 8 == 0)
        int bid = blockIdx.x;
        int virt = (bid & 7) * 588 + (bid >> 3);
        mt = virt / 3; nblk = virt - mt * 3;
    } else { mt = blockIdx.x; nblk = 0; }
    const int t = threadIdx.x, w = t >> 6, lane = t & 63, l15 = lane & 15, lc = lane >> 4;
    const int nfr = (MODE == 0) ? 36 : 12;

    // A staging: thread owns slots t and t+256; slot s: frag f=s>>6, lc=(s>>4)&3, l15=s&15
    const int sl15 = t & 15, slc = (t >> 4) & 3;
    const int m0g = mt * 128 + w * 16 + sl15;
    const int m1g = m0g + 64;
    const size_t abase0 = (size_t)(MODE == 0 ? arow_off_qkv(m0g) : m0g * CC) + slc * 8;
    const size_t abase1 = (size_t)(MODE == 0 ? arow_off_qkv(m1g) : m1g * CC) + slc * 8;

    f32x4 acc[4][6];
    #pragma unroll
    for (int mi = 0; mi < 4; ++mi)
        #pragma unroll
        for (int ni = 0; ni < 6; ++ni) acc[mi][ni] = (f32x4){0.f, 0.f, 0.f, 0.f};

    const int mh = w >> 1, nh = w & 1;

    for (int kt = 0; kt < 6; ++kt) {
        // B: reg-staged fragment loads (weights stay L2-resident; 3 slots/thread)
        {
            const size_t gb = ((size_t)(kt * nfr) + nblk * 12) * 512;
            #pragma unroll
            for (int u = 0; u < 3; ++u) {
                const int s = t + u * 256;
                BhS[s] = *reinterpret_cast<const s16x8*>(Wh + gb + (size_t)s * 8);
                BlS[s] = *reinterpret_cast<const s16x8*>(Wl + gb + (size_t)s * 8);
            }
        }
        // A: reg-stage fp32 + in-register hi/lo split
        float4 x0 = *reinterpret_cast<const float4*>(Asrc + abase0 + kt * 32);
        float4 x1 = *reinterpret_cast<const float4*>(Asrc + abase0 + kt * 32 + 4);
        float4 y0 = *reinterpret_cast<const float4*>(Asrc + abase1 + kt * 32);
        float4 y1 = *reinterpret_cast<const float4*>(Asrc + abase1 + kt * 32 + 4);
        float xv[8] = {x0.x, x0.y, x0.z, x0.w, x1.x, x1.y, x1.z, x1.w};
        float yv[8] = {y0.x, y0.y, y0.z, y0.w, y1.x, y1.y, y1.z, y1.w};
        s16x8 xh, xl, yh, yl;
        #pragma unroll
        for (int j = 0; j < 8; ++j) {
            unsigned short h0 = bfh(xv[j]); xh[j] = (short)h0; xl[j] = (short)bfh(xv[j] - bff(h0));
            unsigned short h1 = bfh(yv[j]); yh[j] = (short)h1; yl[j] = (short)bfh(yv[j] - bff(h1));
        }
        AhS[t] = xh; AlS[t] = xl; AhS[t + 256] = yh; AlS[t + 256] = yl;
        __syncthreads();

        s16x8 fah[4], fal[4], fbh[6], fbl[6];
        #pragma unroll
        for (int mi = 0; mi < 4; ++mi) {
            fah[mi] = AhS[(mh * 4 + mi) * 64 + lane];
            fal[mi] = AlS[(mh * 4 + mi) * 64 + lane];
        }
        #pragma unroll
        for (int ni = 0; ni < 6; ++ni) {
            fbh[ni] = BhS[(nh * 6 + ni) * 64 + lane];
            fbl[ni] = BlS[(nh * 6 + ni) * 64 + lane];
        }
        // D = W-frag * X-frag  (C^T): term-major for MFMA independence
        #pragma unroll
        for (int mi = 0; mi < 4; ++mi)
            #pragma unroll
            for (int ni = 0; ni < 6; ++ni) MFMA_BF16(acc[mi][ni], fbh[ni], fah[mi]);
        #pragma unroll
        for (int mi = 0; mi < 4; ++mi)
            #pragma unroll
            for (int ni = 0; ni < 6; ++ni) MFMA_BF16(acc[mi][ni], fbh[ni], fal[mi]);
        #pragma unroll
        for (int mi = 0; mi < 4; ++mi)
            #pragma unroll
            for (int ni = 0; ni < 6; ++ni) MFMA_BF16(acc[mi][ni], fbl[ni], fah[mi]);
        __syncthreads();
    }

    // epilogue: C^T D-layout: lane -> C[m = mtile + l15][n = ntile + lc*4 + r]
    #pragma unroll
    for (int mi = 0; mi < 4; ++mi) {
        const int m = mt * 128 + mh * 64 + mi * 16 + l15;
        const int win = m / NTOK, tok = m - win * NTOK;
        if (MODE == 0) {
            const int s = tok >> 5, lcv = (tok >> 3) & 3, jv = tok & 7; // V coords
            const int qt = tok >> 4, l15f = tok & 15;                  // Q/K coords
            #pragma unroll
            for (int ni = 0; ni < 6; ++ni) {
                const int cb = nh * 96 + ni * 16 + lc * 4;     // col-in-192 of r=0
                const int head = cb >> 5, d0 = cb & 31;
                const size_t task = (size_t)(win * NHEAD + head);
                float4 b4 = *reinterpret_cast<const float4*>(bias + nblk * 192 + cb);
                float vv[4] = {acc[mi][ni][0] + b4.x, acc[mi][ni][1] + b4.y,
                               acc[mi][ni][2] + b4.z, acc[mi][ni][3] + b4.w};
                if (nblk == 0) {
                    #pragma unroll
                    for (int r = 0; r < 4; ++r) vv[r] *= QSCALE;
                }
                if (nblk < 2) {
                    short* pl = (nblk == 0) ? qpl : kpl;
                    short* dst = pl + (task * 4 + qt) * 512 + (d0 >> 3) * 128 + l15f * 8 + (d0 & 7);
                    uint2 pk;
                    pk.x = (unsigned)bfh(vv[0]) | ((unsigned)bfh(vv[1]) << 16);
                    pk.y = (unsigned)bfh(vv[2]) | ((unsigned)bfh(vv[3]) << 16);
                    *reinterpret_cast<uint2*>(dst) = pk;
                } else {
                    const int niv = d0 >> 4, l15v0 = d0 & 15;
                    size_t vb = ((task * 2 + s) * 2 + niv) * 512 + lcv * 128 + jv;
                    #pragma unroll
                    for (int r = 0; r < 4; ++r)
                        vpl[vb + (size_t)(l15v0 + r) * 8] = (short)bfh(vv[r]);
                }
            }
        } else {
            const int b = win >> 8, wib = win & 255;
            const int ih = tok / 7, iw = tok - ih * 7;
            int fh = (wib >> 4) * 7 + ih + 3; if (fh >= IMG) fh -= IMG;
            int fw = (wib & 15) * 7 + iw + 3; if (fw >= IMG) fw -= IMG;
            float* orow = outp + ((size_t)((b * IMG + fh) * IMG + fw)) * CC;
            #pragma unroll
            for (int ni = 0; ni < 6; ++ni) {
                const int cb = nh * 96 + ni * 16 + lc * 4;
                float4 b4 = *reinterpret_cast<const float4*>(bias + cb);
                float4 vv = {acc[mi][ni][0] + b4.x, acc[mi][ni][1] + b4.y,
                             acc[mi][ni][2] + b4.z, acc[mi][ni][3] + b4.w};
                *reinterpret_cast<float4*>(orow + cb) = vv;
            }
        }
    }
}

// ---------------- MFMA attention: 1 wave per (window, head) ----------------
// S^T = K*Q^T (lane-local softmax), P regrouped via single-wave LDS, O = P*V
__global__ __launch_bounds__(64)
void attn(const short* __restrict__ qpl, const short* __restrict__ kpl,
          const short* __restrict__ vpl, const float* __restrict__ tbl,
          float* __restrict__ Ows) {
    __shared__ unsigned int FR[2048]; // 8KB: [s][qt][lane][dword]
    const int win = blockIdx.x, h = blockIdx.y;
    const int lane = threadIdx.x, l15 = lane & 15, lc = lane >> 4;
    const size_t tq = (size_t)(win * NHEAD + h) * 2048; // u16

    s16x8 qf[4], kf[4], vf[2][2];
    #pragma unroll
    for (int qt = 0; qt < 4; ++qt) {
        qf[qt] = *reinterpret_cast<const s16x8*>(qpl + tq + (qt * 64 + lane) * 8);
        kf[qt] = *reinterpret_cast<const s16x8*>(kpl + tq + (qt * 64 + lane) * 8);
    }
    #pragma unroll
    for (int s = 0; s < 2; ++s)
        #pragma unroll
        for (int ni = 0; ni < 2; ++ni)
            vf[s][ni] = *reinterpret_cast<const s16x8*>(vpl + tq + ((s * 2 + ni) * 64 + lane) * 8);

    // S^T tiles: lane -> S[q = qt*16+l15][k = kt*16+lc*4+r]
    f32x4 st[4][4];
    #pragma unroll
    for (int kt = 0; kt < 4; ++kt)
        #pragma unroll
        for (int qt = 0; qt < 4; ++qt) {
            st[kt][qt] = (f32x4){0.f, 0.f, 0.f, 0.f};
            MFMA_BF16(st[kt][qt], kf[kt], qf[qt]);
        }

    // + rel-pos bias + shift mask + k-padding (precomputed table, 4 window classes)
    const int wib = win & 255;
    const int cls = (((wib >> 4) == 15) ? 2 : 0) + (((wib & 15) == 15) ? 1 : 0);
    const float* tb = tbl + ((h * 4 + cls) << 12);
    #pragma unroll
    for (int kt = 0; kt < 4; ++kt)
        #pragma unroll
        for (int qt = 0; qt < 4; ++qt)
            #pragma unroll
            for (int r = 0; r < 4; ++r)
                st[kt][qt][r] += tb[(kt * 16 + lc * 4 + r) * 64 + qt * 16 + l15];

    // softmax per q-column (reduce across lc via xor16/xor32; rest lane-local)
    float inv[4];
    #pragma unroll
    for (int qt = 0; qt < 4; ++qt) {
        float mx = st[0][qt][0];
        #pragma unroll
        for (int kt = 0; kt < 4; ++kt)
            #pragma unroll
            for (int r = 0; r < 4; ++r) mx = fmaxf(mx, st[kt][qt][r]);
        mx = fmaxf(mx, __shfl_xor(mx, 16));
        mx = fmaxf(mx, __shfl_xor(mx, 32));
        float sum = 0.f;
        #pragma unroll
        for (int kt = 0; kt < 4; ++kt)
            #pragma unroll
            for (int r = 0; r < 4; ++r) {
                float e = __expf(st[kt][qt][r] - mx);
                st[kt][qt][r] = e; sum += e;
            }
        sum += __shfl_xor(sum, 16);
        sum += __shfl_xor(sum, 32);
        inv[qt] = 1.0f / sum;
    }

    // P -> bf16, regroup D-layout (k = kt*16+lc*4+r) into A-frags (k = s*32+lc*8+j) via LDS
    #pragma unroll
    for (int kt = 0; kt < 4; ++kt)
        #pragma unroll
        for (int qt = 0; qt < 4; ++qt) {
            float p0 = st[kt][qt][0] * inv[qt], p1 = st[kt][qt][1] * inv[qt];
            float p2 = st[kt][qt][2] * inv[qt], p3 = st[kt][qt][3] * inv[qt];
            unsigned pk01 = (unsigned)bfh(p0) | ((unsigned)bfh(p1) << 16);
            unsigned pk23 = (unsigned)bfh(p2) | ((unsigned)bfh(p3) << 16);
            int tl = ((kt & 1) * 2 + (lc >> 1)) * 16 + l15;
            int base = (((kt >> 1) * 4 + qt) * 64 + tl) * 4 + (lc & 1) * 2;
            FR[base] = pk01; FR[base + 1] = pk23;
        }
    __syncthreads();
    s16x8 pa[2][4];
    #pragma unroll
    for (int s = 0; s < 2; ++s)
        #pragma unroll
        for (int qt = 0; qt < 4; ++qt)
            pa[s][qt] = *reinterpret_cast<const s16x8*>(&FR[((s * 4 + qt) * 64 + lane) * 4]);

    // O = P*V : lane -> O[q = qt*16+lc*4+r][d = ni*16+l15]
    f32x4 o[4][2];
    #pragma unroll
    for (int qt = 0; qt < 4; ++qt)
        #pragma unroll
        for (int ni = 0; ni < 2; ++ni) o[qt][ni] = (f32x4){0.f, 0.f, 0.f, 0.f};
    #pragma unroll
    for (int s = 0; s < 2; ++s)
        #pragma unroll
        for (int qt = 0; qt < 4; ++qt)
            #pragma unroll
            for (int ni = 0; ni < 2; ++ni)
                MFMA_BF16(o[qt][ni], pa[s][qt], vf[s][ni]);

    const size_t obase = (size_t)win * NTOK * CC + h * HD;
    #pragma unroll
    for (int qt = 0; qt < 4; ++qt)
        #pragma unroll
        for (int r = 0; r < 4; ++r) {
            int qrow = qt * 16 + lc * 4 + r;
            if (qrow < NTOK) {
                #pragma unroll
                for (int ni = 0; ni < 2; ++ni)
                    Ows[obase + (size_t)qrow * CC + ni * 16 + l15] = o[qt][ni][r];
            }
        }
}

// ---------------- launcher ----------------
extern "C" void kernel_launch(void* const* d_in, const int* in_sizes, int n_in,
                              void* d_out, int out_size, void* d_ws, size_t ws_size,
                              hipStream_t stream) {
    const float* x     = (const float*)d_in[0];
    const float* qkvw  = (const float*)d_in[1];
    const float* qkvb  = (const float*)d_in[2];
    const float* projw = (const float*)d_in[3];
    const float* projb = (const float*)d_in[4];
    const float* relb  = (const float*)d_in[5];

    char* ws = (char*)d_ws;
    short* qpl = (short*)ws;                                   // 100,663,296 B
    short* kpl = qpl + PLANE_U16;
    short* vpl = kpl + PLANE_U16;
    float* Ows = (float*)(vpl + PLANE_U16);                    // 154,140,672 B
    short* wqh = (short*)(Ows + (size_t)MTOK * CC);
    short* wql = wqh + (size_t)WQ_SLOTS * 8;
    short* wph = wql + (size_t)WQ_SLOTS * 8;
    short* wpl_ = wph + (size_t)WP_SLOTS * 8;
    float* tbl = (float*)(wpl_ + (size_t)WP_SLOTS * 8);        // 393,216 B
    // total ws: ~457.1 MB (round-1 proved >= 616 MB available)

    prep<<<456, 256, 0, stream>>>(qkvw, projw, relb, wqh, wql, wph, wpl_, tbl);
    gemm_swapped<0><<<4704, 256, 0, stream>>>(x, wqh, wql, qkvb, qpl, kpl, vpl, nullptr);
    attn<<<dim3(TOTWIN, NHEAD), 64, 0, stream>>>(qpl, kpl, vpl, tbl, Ows);
    gemm_swapped<1><<<1568, 256, 0, stream>>>(Ows, wph, wpl_, projb, nullptr, nullptr, nullptr,
                                              (float*)d_out);
}